// Round 7
// baseline (253.425 us; speedup 1.0000x reference)
//
#include <hip/hip_runtime.h>
#include <cstdint>

// ViT patch embedding, two-stage.
//   prep_all:  image-linear patchify+cvt -> bf16 A, W -> bf16 Wb, cls -> out.
//   vit_gemm6: R7 = LDS-free streaming GEMM.
//              R4-R6 post-mortem: all schedule grafts on the LDS-staged
//              structure were null/negative; arithmetic shows R3 is
//              LDS-pipe-bound (~1150 cyc LDS vs 620 cyc MFMA per step) and
//              R5 showed 256^2 per-work efficiency beats 128^2 but dies on
//              grid quantization. Fix: drop LDS entirely. K=768 is tiny,
//              B (1.2MB) is L2-resident, A-panel re-reads are co-XCD L2
//              hits; MFMA frag loads are 16-row x 64B segments served fine
//              by L1/L2. Each wave streams frags global->VGPR (linear
//              addresses, no swizzle), K-half software pipeline, ZERO
//              barriers / staging / LDS. 4-wave 256-thr blocks (wave tile
//              128x64, 8x4 frags), 2 blocks/CU, grid 588 (smooth 2.3/slot),
//              bijective XCD swizzle so the 6 n-blocks of an A-panel
//              co-locate. Same verified fragment mapping and epilogue.

#define PGRID 14
#define PSZ   16
#define CHN   3
#define IMGW  224
#define KDIM  768
#define NDIM  768
#define NPATCH 196

typedef short bf16x8 __attribute__((ext_vector_type(8)));
typedef short short8v __attribute__((ext_vector_type(8)));
typedef float f32x4  __attribute__((ext_vector_type(4)));

__device__ __forceinline__ short bf16rne(float f) {
    uint32_t u = __builtin_bit_cast(uint32_t, f);
    u += 0x7FFFu + ((u >> 16) & 1u);
    return (short)(u >> 16);
}

__device__ __forceinline__ short8v cvt8(float4 v0, float4 v1) {
    short8v s;
    s[0] = bf16rne(v0.x); s[1] = bf16rne(v0.y); s[2] = bf16rne(v0.z); s[3] = bf16rne(v0.w);
    s[4] = bf16rne(v1.x); s[5] = bf16rne(v1.y); s[6] = bf16rne(v1.z); s[7] = bf16rne(v1.w);
    return s;
}

// ---------------- prep: patchify + W convert + cls fill, image-linear ----------------
__global__ __launch_bounds__(256) void prep_all(
    const float* __restrict__ img, const float* __restrict__ Wl,
    const float* __restrict__ cls, short* __restrict__ A,
    short* __restrict__ Wb, float* __restrict__ out, int n_img)
{
    const int IMG8 = n_img * (CHN * IMGW * IMGW / 8);   // n*18816
    const int W8   = KDIM * NDIM / 8;                   // 73728
    int t = blockIdx.x * 256 + threadIdx.x;

    if (t < IMG8) {
        int w8    = t % (IMGW / 8);        // 0..27
        int rest  = t / (IMGW / 8);
        int h     = rest % IMGW;
        int rest2 = rest / IMGW;
        int c     = rest2 % CHN;
        int im    = rest2 / CHN;

        float4 v0 = *(const float4*)(img + (long)t * 8);
        float4 v1 = *(const float4*)(img + (long)t * 8 + 4);

        int Pi = h >> 4;
        int ph = h & 15;
        int Pj = w8 >> 1;
        int pw = (w8 & 1) * 8;
        int m  = im * NPATCH + Pi * PGRID + Pj;
        int k  = (c << 8) + (ph << 4) + pw;
        *(short8v*)(A + (long)m * KDIM + k) = cvt8(v0, v1);
    } else if (t < IMG8 + W8) {
        int u = t - IMG8;
        float4 v0 = *(const float4*)(Wl + (long)u * 8);
        float4 v1 = *(const float4*)(Wl + (long)u * 8 + 4);
        *(short8v*)(Wb + (long)u * 8) = cvt8(v0, v1);
    } else {
        int u = t - IMG8 - W8;
        if (u < n_img * (NDIM / 8)) {
            int im = u / (NDIM / 8);
            int k8 = u - im * (NDIM / 8);
            float4 v0 = *(const float4*)(cls + k8 * 8);
            float4 v1 = *(const float4*)(cls + k8 * 8 + 4);
            float* dst = out + (long)im * 197 * NDIM + k8 * 8;
            *(float4*)dst = v0;
            *(float4*)(dst + 4) = v1;
        }
    }
}

// ---------------- main GEMM: bf16 A[M][768] @ Wb[768][768]^T + bias ----------------
// LDS-free streaming: block 256x128 (4 waves 2m x 2n, wave tile 128x64),
// frags loaded straight from global (L1/L2) into VGPRs, K-half pipeline.
__global__ __launch_bounds__(256, 2) void vit_gemm6(
    const short* __restrict__ A, const short* __restrict__ B,
    const float* __restrict__ bias, float* __restrict__ out,
    int M, int mgroups)
{
    // bijective XCD swizzle (m204): 6 consecutive wgid (one A-panel's
    // n-blocks) land on one XCD.
    const int nwg = mgroups * 6;
    const int q = nwg >> 3, r = nwg & 7;
    const int xcd = blockIdx.x & 7;
    const int idx = blockIdx.x >> 3;
    const int wgid = (xcd < r ? xcd * (q + 1) : r * (q + 1) + (xcd - r) * q) + idx;
    const int g = wgid / 6;            // m-group (256 rows)
    const int j = wgid - g * 6;        // n-group (128 cols)
    const int m0 = g * 256;
    const int n0 = j * 128;

    const int tid  = threadIdx.x;
    const int wave = tid >> 6;
    const int lane = tid & 63;
    const int wr = wave >> 1;          // 0..1 -> m offset
    const int wc = wave & 1;           // 0..1 -> n offset
    const int wm = wr * 128;
    const int wn = wc * 64;
    const int wq = lane >> 4;
    const int lr = lane & 15;

    // per-lane fragment base addresses (elements). Fragment (i, h):
    // A[m0+wm+i*16+lr][h*32... lane k = h*32 + wq*8 .. +8)   (verified map)
    const long arow = (long)(m0 + wm + lr) * KDIM + wq * 8;
    const long brow = (long)(n0 + wn + lr) * KDIM + wq * 8;

    f32x4 acc[8][4] = {};
    bf16x8 a0[8], b0[4], a1[8], b1[4];   // two K-half stages (static names)

#define LOADH(AH, BH, KOFF)                                                  \
    {                                                                        \
        _Pragma("unroll")                                                    \
        for (int i = 0; i < 8; ++i)                                          \
            AH[i] = *(const bf16x8*)(A + arow + (long)i * 16 * KDIM + (KOFF)); \
        _Pragma("unroll")                                                    \
        for (int jm = 0; jm < 4; ++jm)                                       \
            BH[jm] = *(const bf16x8*)(B + brow + (long)jm * 16 * KDIM + (KOFF)); \
    }

#define MFMAH(AH, BH)                                                        \
    {                                                                        \
        _Pragma("unroll")                                                    \
        for (int i = 0; i < 8; ++i)                                          \
            _Pragma("unroll")                                                \
            for (int jm = 0; jm < 4; ++jm)                                   \
                acc[i][jm] = __builtin_amdgcn_mfma_f32_16x16x32_bf16(        \
                    AH[i], BH[jm], acc[i][jm], 0, 0, 0);                     \
    }

    // 24 K-halves (32 wide each), 2-deep register pipeline, no sync at all.
    LOADH(a0, b0, 0)
    #pragma unroll
    for (int kt = 0; kt < 12; ++kt) {
        LOADH(a1, b1, kt * 64 + 32)
        MFMAH(a0, b0)
        if (kt < 11) LOADH(a0, b0, (kt + 1) * 64)
        MFMAH(a1, b1)
    }

#undef LOADH
#undef MFMAH

    float bv[4];
    #pragma unroll
    for (int jm = 0; jm < 4; ++jm) bv[jm] = bias[n0 + wn + jm * 16 + lr];

    #pragma unroll
    for (int i = 0; i < 8; ++i) {
        #pragma unroll
        for (int rr = 0; rr < 4; ++rr) {
            int gm = m0 + wm + i * 16 + wq * 4 + rr;
            if (gm < M) {
                int im = gm / NPATCH;
                int p  = gm - im * NPATCH;
                long orow = ((long)im * 197 + 1 + p) * (long)NDIM;
                #pragma unroll
                for (int jm = 0; jm < 4; ++jm)
                    out[orow + n0 + wn + jm * 16 + lr] = acc[i][jm][rr] + bv[jm];
            }
        }
    }
}

// ---------------- fallback (no ws needed) ----------------
#define LDSTR 40
__global__ __launch_bounds__(256) void vit_gemm_fb(
    const float* __restrict__ img, const float* __restrict__ Wl,
    const float* __restrict__ bias, float* __restrict__ out, int n_img)
{
    const int M = n_img * NPATCH;
    __shared__ short As[128 * LDSTR];
    __shared__ short Bs[128 * LDSTR];
    const int tid = threadIdx.x;
    const int m0 = blockIdx.y * 128;
    const int n0 = blockIdx.x * 128;
    const int col4  = tid & 7;
    const int rbase = tid >> 3;
    long arow[4];
    for (int rr = 0; rr < 4; ++rr) {
        int m = m0 + rbase + rr * 32;
        int mm = (m < M) ? m : (M - 1);
        int im = mm / NPATCH;
        int p  = mm % NPATCH;
        int Pi = p / PGRID;
        int Pj = p % PGRID;
        arow[rr] = ((long)(im * CHN) * IMGW + Pi * PSZ) * IMGW + Pj * PSZ;
    }
    const int lane = tid & 63;
    const int wave = tid >> 6;
    const int wm = (wave & 1) * 64;
    const int wn = (wave >> 1) * 64;
    const int wq = lane >> 4;
    const int lr = lane & 15;
    f32x4 acc[4][4] = {};
    for (int k0 = 0; k0 < KDIM; k0 += 32) {
        {
            int k  = k0 + col4 * 4;
            int c  = k >> 8;
            int ph = (k >> 4) & 15;
            int pw = k & 15;
            long koff = (long)(c * IMGW + ph) * IMGW + pw;
            #pragma unroll
            for (int rr = 0; rr < 4; ++rr) {
                const float4 v = *(const float4*)(img + arow[rr] + koff);
                int row = rbase + rr * 32;
                short4 s;
                s.x = bf16rne(v.x); s.y = bf16rne(v.y);
                s.z = bf16rne(v.z); s.w = bf16rne(v.w);
                *(short4*)(&As[row * LDSTR + col4 * 4]) = s;
            }
        }
        {
            int k = k0 + col4 * 4;
            #pragma unroll
            for (int rr = 0; rr < 4; ++rr) {
                int nrow = rbase + rr * 32;
                const float4 v = *(const float4*)(Wl + (long)(n0 + nrow) * KDIM + k);
                short4 s;
                s.x = bf16rne(v.x); s.y = bf16rne(v.y);
                s.z = bf16rne(v.z); s.w = bf16rne(v.w);
                *(short4*)(&Bs[nrow * LDSTR + col4 * 4]) = s;
            }
        }
        __syncthreads();
        bf16x8 a[4], b[4];
        #pragma unroll
        for (int i = 0; i < 4; ++i)
            a[i] = *(const bf16x8*)(&As[(wm + i * 16 + lr) * LDSTR + wq * 8]);
        #pragma unroll
        for (int i = 0; i < 4; ++i)
            b[i] = *(const bf16x8*)(&Bs[(wn + i * 16 + lr) * LDSTR + wq * 8]);
        #pragma unroll
        for (int i = 0; i < 4; ++i)
            #pragma unroll
            for (int j = 0; j < 4; ++j)
                acc[i][j] = __builtin_amdgcn_mfma_f32_16x16x32_bf16(a[i], b[j], acc[i][j], 0, 0, 0);
        __syncthreads();
    }
    float bv[4];
    #pragma unroll
    for (int j = 0; j < 4; ++j) bv[j] = bias[n0 + wn + j * 16 + lr];
    #pragma unroll
    for (int i = 0; i < 4; ++i) {
        #pragma unroll
        for (int r = 0; r < 4; ++r) {
            int gm = m0 + wm + i * 16 + wq * 4 + r;
            if (gm < M) {
                int im = gm / NPATCH;
                int p  = gm % NPATCH;
                long orow = ((long)im * 197 + 1 + p) * (long)NDIM;
                #pragma unroll
                for (int j = 0; j < 4; ++j)
                    out[orow + n0 + wn + j * 16 + lr] = acc[i][j][r] + bv[j];
            }
        }
    }
}

__global__ __launch_bounds__(256) void cls_fill(
    const float* __restrict__ cls, float* __restrict__ out, int n_img)
{
    int i = blockIdx.x * 256 + threadIdx.x;
    if (i < n_img * NDIM) {
        int im = i / NDIM;
        int n  = i - im * NDIM;
        out[(long)im * 197 * NDIM + n] = cls[n];
    }
}

extern "C" void kernel_launch(void* const* d_in, const int* in_sizes, int n_in,
                              void* d_out, int out_size, void* d_ws, size_t ws_size,
                              hipStream_t stream) {
    const float* img  = (const float*)d_in[0];
    const float* Wl   = (const float*)d_in[1];
    const float* bias = (const float*)d_in[2];
    const float* cls  = (const float*)d_in[3];
    float* out = (float*)d_out;

    int n_img = in_sizes[0] / (CHN * IMGW * IMGW);
    int M = n_img * NPATCH;
    int mgroups = (M + 255) / 256;
    long Mpad = (long)mgroups * 256;

    size_t need = (size_t)(Mpad * KDIM + (long)KDIM * NDIM) * sizeof(short);
    if (ws_size >= need) {
        short* A_ws = (short*)d_ws;
        short* Wb   = A_ws + Mpad * KDIM;

        int total8 = n_img * (CHN * IMGW * IMGW / 8)
                   + KDIM * NDIM / 8
                   + n_img * (NDIM / 8);
        prep_all<<<(total8 + 255) / 256, 256, 0, stream>>>(img, Wl, cls, A_ws, Wb, out, n_img);

        int nwg = mgroups * 6;
        vit_gemm6<<<nwg, 256, 0, stream>>>(A_ws, Wb, bias, out, M, mgroups);
    } else {
        dim3 grid(NDIM / 128, (M + 127) / 128);
        vit_gemm_fb<<<grid, 256, 0, stream>>>(img, Wl, bias, out, n_img);
        int cls_elems = n_img * NDIM;
        cls_fill<<<(cls_elems + 255) / 256, 256, 0, stream>>>(cls, out, n_img);
    }
}